// Round 14
// baseline (398.353 us; speedup 1.0000x reference)
//
#include <hip/hip_runtime.h>
#include <cstddef>

#define NN 1024
#define DD 6
#define TT 60
#define HH 64
#define NEGV  (-10000.0f)
#define SLOPEV (0.01f)
#define GRUB 64           // GRU blocks: 16 samples, 8 waves (512 thr)
#define RELB 448          // rel blocks: 64+448 = 512 = exactly 2/CU, ONE generation

// LDS float offsets
#define PA_RZ 0           // L0 r,z preacts [row 0..127][19]
#define PA_XN 2432        // L0 xn [row 0..63][19]
#define PA_HN 3648        // L0 hn
#define PB_RZ 4864        // L1 r,z preacts
#define PB_XN 7296        // L1 xn
#define PB_HN 8512        // L1 hn
#define HF0   9728        // h0 f32 [j][19]
#define HF1   10944       // h1 f32 [j][19]
#define BH0   12160       // h0 f16 [n][72]
#define BH1   12736       // h1 f16 [n][72]
#define XH    13312       // x f16 [(t*16+n)*8]
#define SMEMF 17152       // 68.6 KB -> 2 blocks/CU

typedef _Float16 v8h __attribute__((ext_vector_type(8)));
typedef float    v4f __attribute__((ext_vector_type(4)));

#define MF(a, b, c) __builtin_amdgcn_mfma_f32_16x16x32_f16((a), (b), (c), 0, 0, 0)

__device__ __forceinline__ float sig_(float x)  { return 1.0f / (1.0f + __expf(-x)); }
__device__ __forceinline__ float tanh_(float x) { return 1.0f - 2.0f / (__expf(2.0f * x) + 1.0f); }
__device__ __forceinline__ float bcf_(const float a, const float b) {
    return __builtin_bit_cast(float, __builtin_amdgcn_cvt_pkrtz(a, b));
}
__device__ __forceinline__ v8h zero8() {
    v8h r;
    #pragma unroll
    for (int j = 0; j < 8; ++j) r[j] = (_Float16)0.f;
    return r;
}
__device__ __forceinline__ v8h pack8(const float* __restrict__ p) {
    v8h r;
    #pragma unroll
    for (int j = 0; j < 8; ++j) r[j] = (_Float16)p[j];
    return r;
}
__device__ __forceinline__ v8h pack6(const float* __restrict__ p) {
    v8h r = zero8();
    #pragma unroll
    for (int j = 0; j < 6; ++j) r[j] = (_Float16)p[j];
    return r;
}

// ---------------------------------------------------------------------------
// k_main: 512 blocks x 512 threads — ALL co-resident (2/CU), one generation.
//   blocks [0,64)  : MFMA GRU, 16 samples, 8 waves, software-pipelined:
//     MM phase : waves 0-3 = L0 tiles for t=i; waves 4-7 = L1 tiles for t=i-1.
//     UPD phase: thr 0-255 update h0(i); thr 256-511 update h1(i-1).
//     2 barriers/step. (R13: 960-block grid ran rel in 2 serial generations —
//     this round's only change is the single-generation grid.)
//   blocks [64,512): rel streaming, ~4.6 pairs/thread, no barriers; their
//     HBM stalls co-schedule with GRU barrier gaps on shared CUs.
// ---------------------------------------------------------------------------
__global__ __launch_bounds__(512)
void k_main(const float* __restrict__ x, const float* __restrict__ rel,
            const float* __restrict__ W, const float* __restrict__ fc_w,
            const float* __restrict__ Wih0, const float* __restrict__ Whh0,
            const float* __restrict__ bih0, const float* __restrict__ bhh0,
            const float* __restrict__ Wih1, const float* __restrict__ Whh1,
            const float* __restrict__ bih1, const float* __restrict__ bhh1,
            float* __restrict__ sa, float* __restrict__ sb,
            float* __restrict__ hdot, float* __restrict__ hb,
            float* __restrict__ sr, float* __restrict__ ssum)
{
    __shared__ float smem[SMEMF];
    const int tid = threadIdx.x;

    if (blockIdx.x >= GRUB) {
        // ---------------- relation streaming ----------------
        const float* __restrict__ Wv = W + 2 * HH;     // uniform -> s_loads
        const unsigned base = (unsigned)(blockIdx.x - GRUB) * 512 + tid;
        for (unsigned p = base; p < (unsigned)(NN * NN); p += (unsigned)RELB * 512) {
            const float4* b4 = (const float4*)(rel + (size_t)p * 64);
            float4 v[16];
            #pragma unroll
            for (int q = 0; q < 16; ++q) v[q] = b4[q];
            float d0 = 0.f, d1 = 0.f, s0 = 0.f, s1 = 0.f;
            #pragma unroll
            for (int q = 0; q < 16; ++q) {
                d0 += v[q].x * Wv[4*q]   + v[q].z * Wv[4*q+2];
                d1 += v[q].y * Wv[4*q+1] + v[q].w * Wv[4*q+3];
                s0 += v[q].x + v[q].z;
                s1 += v[q].y + v[q].w;
            }
            sr[p]   = d0 + d1;
            ssum[p] = s0 + s1;
        }
        return;
    }

    // ---------------- GRU ----------------
    const int w    = tid >> 6;          // wave 0..7
    const int lane = tid & 63;
    const int quad = lane >> 4;
    const int mc   = lane & 15;
    const int nb   = blockIdx.x * 16;
    const bool isL0 = (w < 4);
    const int wt   = isL0 ? w : (w - 4);   // row-tile index within layer

    // ---- stage x as f16 ----
    for (int idx = tid; idx < TT * 16; idx += 512) {
        const int t = idx >> 4, n = idx & 15;
        const float* xp = x + (size_t)(nb + n) * (DD * TT) + t;
        float4 pk;
        pk.x = bcf_(xp[0],   xp[60]);
        pk.y = bcf_(xp[120], xp[180]);
        pk.z = bcf_(xp[240], xp[300]);
        pk.w = 0.f;
        *(float4*)(smem + XH + idx * 4) = pk;
    }
    for (int idx = tid; idx < 1152; idx += 512) smem[BH0 + idx] = 0.f;
    for (int idx = tid; idx < 2432; idx += 512) smem[HF0 + idx] = 0.f;

    // ---- per-role persistent A-fragments ----
    const int r0row = 16 * wt + mc;
    const int zrow  = 64 + 16 * wt + mc;
    const int nrow  = 128 + 16 * wt + mc;
    v8h F0 = zero8(), F1 = zero8(), F2 = zero8(), F3 = zero8();
    v8h F4 = zero8(), F5 = zero8(), F6 = zero8(), F7 = zero8();
    v8h F8 = zero8(), F9 = zero8(), F10 = zero8(), F11 = zero8();
    v8h Xr = zero8(), Xz = zero8(), Xn = zero8();
    if (isL0) {
        F0 = pack8(Whh0 + (size_t)r0row * HH + quad * 8);         // Ar0
        F1 = pack8(Whh0 + (size_t)r0row * HH + 32 + quad * 8);    // Ar1
        F2 = pack8(Whh0 + (size_t)zrow  * HH + quad * 8);         // Az0
        F3 = pack8(Whh0 + (size_t)zrow  * HH + 32 + quad * 8);    // Az1
        F4 = pack8(Whh0 + (size_t)nrow  * HH + quad * 8);         // An0
        F5 = pack8(Whh0 + (size_t)nrow  * HH + 32 + quad * 8);    // An1
        if (quad == 0) {
            Xr = pack6(Wih0 + r0row * DD);
            Xz = pack6(Wih0 + zrow  * DD);
            Xn = pack6(Wih0 + nrow  * DD);
        }
    } else {
        F0 = pack8(Wih1 + (size_t)r0row * HH + quad * 8);         // R0
        F1 = pack8(Wih1 + (size_t)r0row * HH + 32 + quad * 8);    // R1
        F2 = pack8(Whh1 + (size_t)r0row * HH + quad * 8);         // R2
        F3 = pack8(Whh1 + (size_t)r0row * HH + 32 + quad * 8);    // R3
        F4 = pack8(Wih1 + (size_t)zrow * HH + quad * 8);          // Z0
        F5 = pack8(Wih1 + (size_t)zrow * HH + 32 + quad * 8);     // Z1
        F6 = pack8(Whh1 + (size_t)zrow * HH + quad * 8);          // Z2
        F7 = pack8(Whh1 + (size_t)zrow * HH + 32 + quad * 8);     // Z3
        F8 = pack8(Wih1 + (size_t)nrow * HH + quad * 8);          // Nx0
        F9 = pack8(Wih1 + (size_t)nrow * HH + 32 + quad * 8);     // Nx1
        F10 = pack8(Whh1 + (size_t)nrow * HH + quad * 8);         // Nh0
        F11 = pack8(Whh1 + (size_t)nrow * HH + 32 + quad * 8);    // Nh1
    }

    // ---- biases at C rows ----
    float bR[4], bZ[4], bXn[4], bHn[4];
    #pragma unroll
    for (int e = 0; e < 4; ++e) {
        const int cr = 16 * wt + quad * 4 + e;
        if (isL0) {
            bR[e]  = bih0[cr] + bhh0[cr];
            bZ[e]  = bih0[64 + cr] + bhh0[64 + cr];
            bXn[e] = bih0[128 + cr];
            bHn[e] = bhh0[128 + cr];
        } else {
            bR[e]  = bih1[cr] + bhh1[cr];
            bZ[e]  = bih1[64 + cr] + bhh1[64 + cr];
            bXn[e] = bih1[128 + cr];
            bHn[e] = bhh1[128 + cr];
        }
    }
    __syncthreads();

    auto ldb = [&](int BH, int win) -> v8h {
        return __builtin_bit_cast(v8h,
            *(const float4*)(smem + BH + mc * 36 + win * 16 + quad * 4));
    };
    auto stC = [&](int base, int rowbase, v4f c) {
        #pragma unroll
        for (int e = 0; e < 4; ++e)
            smem[base + (rowbase + quad * 4 + e) * 19 + mc] = c[e];
    };
    auto upd = [&](int PRZ, int PXN, int PHN, int HF, int BH, int lt) {
        const int n = lt & 15, jb = (lt >> 4) * 4;
        float hv[4];
        #pragma unroll
        for (int e = 0; e < 4; ++e) {
            const int j = jb + e;
            const float rp = smem[PRZ + j * 19 + n];
            const float zp = smem[PRZ + (64 + j) * 19 + n];
            const float xn = smem[PXN + j * 19 + n];
            const float hn = smem[PHN + j * 19 + n];
            const float hp = smem[HF + j * 19 + n];
            const float r  = sig_(rp), z = sig_(zp);
            const float nv = tanh_(xn + r * hn);
            const float h  = (1.f - z) * nv + z * hp;
            smem[HF + j * 19 + n] = h;
            hv[e] = h;
        }
        float2 pk;
        pk.x = bcf_(hv[0], hv[1]);
        pk.y = bcf_(hv[2], hv[3]);
        *(float2*)(smem + BH + n * 36 + (jb >> 1)) = pk;
    };

    for (int i = 0; i <= TT; ++i) {
        // ---------------- MM phase (L0 for t=i, L1 for t=i-1) ----------------
        if (isL0) {
            if (i < TT) {
                const v8h b0 = ldb(BH0, 0);
                const v8h b1 = ldb(BH0, 1);
                const float4 xl = *(const float4*)(smem + XH + (i * 16 + mc) * 4);
                v8h bx = zero8();
                if (quad == 0) bx = __builtin_bit_cast(v8h, xl);

                v4f c = {bR[0], bR[1], bR[2], bR[3]};
                c = MF(F0, b0, c); c = MF(F1, b1, c); c = MF(Xr, bx, c);
                stC(PA_RZ, 16 * wt, c);
                v4f cz = {bZ[0], bZ[1], bZ[2], bZ[3]};
                cz = MF(F2, b0, cz); cz = MF(F3, b1, cz); cz = MF(Xz, bx, cz);
                stC(PA_RZ, 64 + 16 * wt, cz);
                v4f ch = {bHn[0], bHn[1], bHn[2], bHn[3]};
                ch = MF(F4, b0, ch); ch = MF(F5, b1, ch);
                stC(PA_HN, 16 * wt, ch);
                v4f cx = {bXn[0], bXn[1], bXn[2], bXn[3]};
                cx = MF(Xn, bx, cx);
                stC(PA_XN, 16 * wt, cx);
            }
        } else {
            if (i >= 1) {
                const v8h g0 = ldb(BH0, 0);        // h0 after t=i-1
                const v8h g1 = ldb(BH0, 1);
                const v8h g2 = ldb(BH1, 0);        // h1 after t=i-2
                const v8h g3 = ldb(BH1, 1);

                v4f c = {bR[0], bR[1], bR[2], bR[3]};
                c = MF(F0, g0, c); c = MF(F1, g1, c); c = MF(F2, g2, c); c = MF(F3, g3, c);
                stC(PB_RZ, 16 * wt, c);
                v4f cz = {bZ[0], bZ[1], bZ[2], bZ[3]};
                cz = MF(F4, g0, cz); cz = MF(F5, g1, cz); cz = MF(F6, g2, cz); cz = MF(F7, g3, cz);
                stC(PB_RZ, 64 + 16 * wt, cz);
                v4f cx = {bXn[0], bXn[1], bXn[2], bXn[3]};
                cx = MF(F8, g0, cx); cx = MF(F9, g1, cx);
                stC(PB_XN, 16 * wt, cx);
                v4f ch = {bHn[0], bHn[1], bHn[2], bHn[3]};
                ch = MF(F10, g2, ch); ch = MF(F11, g3, ch);
                stC(PB_HN, 16 * wt, ch);
            }
        }
        __syncthreads();
        // ---------------- UPD phase ----------------
        if (tid < 256) {
            if (i < TT) upd(PA_RZ, PA_XN, PA_HN, HF0, BH0, tid);
        } else {
            if (i >= 1) upd(PB_RZ, PB_XN, PB_HN, HF1, BH1, tid - 256);
        }
        __syncthreads();
    }

    // ---------------- epilogue: 4 scalars x 16 samples (waves 0-3) ----------
    if (w < 4) {
        const int n = lane >> 2, p = lane & 3;
        const float* __restrict__ wp = (w == 0) ? W : (w == 1) ? (W + HH)
                                     : (w == 2) ? fc_w : (fc_w + HH);
        float v = 0.f;
        #pragma unroll
        for (int q = 0; q < 16; ++q) {
            const int j = p * 16 + q;
            v += smem[HF1 + j * 19 + n] * wp[j];
        }
        v += __shfl_down(v, 2);
        v += __shfl_down(v, 1);
        if (p == 0) {
            float* dst = (w == 0) ? sa : (w == 1) ? sb : (w == 2) ? hdot : hb;
            dst[nb + n] = v;
        }
    }
}

// ---------------------------------------------------------------------------
// k2: per row i — masked leaky scores, exact masked-softmax semantics,
// out_i = hdot_i + (sum_j e_j*m_j*hb_j)/denom + fc_b.   (verified R2-R13)
// ---------------------------------------------------------------------------
__global__ __launch_bounds__(256)
void k2(const float* __restrict__ sa, const float* __restrict__ sb,
        const float* __restrict__ hdot, const float* __restrict__ hb,
        const float* __restrict__ sr, const float* __restrict__ ssum,
        const float* __restrict__ bscal, const float* __restrict__ fc_b,
        float* __restrict__ out)
{
    __shared__ float red[12];
    const int i   = blockIdx.x;
    const int tid = threadIdx.x;
    const int j4  = tid * 4;
    const float sai = sa[i] + bscal[0];

    const float4 srv = *(const float4*)(sr   + (size_t)i * NN + j4);
    const float4 ssv = *(const float4*)(ssum + (size_t)i * NN + j4);
    const float4 sbv = *(const float4*)(sb + j4);

    float tv[4], mk[4];
    float mloc = -3.4e38f;
    {
        const float srq[4] = {srv.x, srv.y, srv.z, srv.w};
        const float ssq[4] = {ssv.x, ssv.y, ssv.z, ssv.w};
        const float sbq[4] = {sbv.x, sbv.y, sbv.z, sbv.w};
        #pragma unroll
        for (int q = 0; q < 4; ++q) {
            float wv = sai + sbq[q] + srq[q];
            wv = (wv >= 0.0f) ? wv : SLOPEV * wv;
            const float m = (ssq[q] != 0.0f) ? 1.0f : 0.0f;
            float tt = m * wv;
            tt = (tt == 0.0f) ? NEGV : tt;
            tv[q] = tt; mk[q] = m;
            mloc = fmaxf(mloc, tt);
        }
    }
    #pragma unroll
    for (int off = 32; off >= 1; off >>= 1) mloc = fmaxf(mloc, __shfl_xor(mloc, off));
    if ((tid & 63) == 0) red[tid >> 6] = mloc;
    __syncthreads();
    const float mx = fmaxf(fmaxf(red[0], red[1]), fmaxf(red[2], red[3]));

    const float4 hbv = *(const float4*)(hb + j4);
    const float hbq[4] = {hbv.x, hbv.y, hbv.z, hbv.w};
    float sloc = 0.0f, vloc = 0.0f;
    #pragma unroll
    for (int q = 0; q < 4; ++q) {
        const float e = __expf(tv[q] - mx);   // masked -> exp(-1e4 - mx) == 0
        sloc += e;
        vloc += e * mk[q] * hbq[q];
    }
    #pragma unroll
    for (int off = 32; off >= 1; off >>= 1) {
        sloc += __shfl_xor(sloc, off);
        vloc += __shfl_xor(vloc, off);
    }
    if ((tid & 63) == 0) { red[4 + (tid >> 6)] = sloc; red[8 + (tid >> 6)] = vloc; }
    __syncthreads();
    if (tid == 0) {
        const float denom = red[4] + red[5] + red[6] + red[7];
        const float vsum  = red[8] + red[9] + red[10] + red[11];
        out[i] = hdot[i] + vsum / denom + fc_b[0];
    }
}

// ---------------------------------------------------------------------------
extern "C" void kernel_launch(void* const* d_in, const int* in_sizes, int n_in,
                              void* d_out, int out_size, void* d_ws, size_t ws_size,
                              hipStream_t stream)
{
    const float* x     = (const float*)d_in[0];
    const float* rel   = (const float*)d_in[1];
    const float* W     = (const float*)d_in[2];
    const float* b     = (const float*)d_in[3];
    const float* fc_w  = (const float*)d_in[4];
    const float* fc_b  = (const float*)d_in[5];
    const float* Wih0  = (const float*)d_in[6];
    const float* Whh0  = (const float*)d_in[7];
    const float* bih0  = (const float*)d_in[8];
    const float* bhh0  = (const float*)d_in[9];
    const float* Wih1  = (const float*)d_in[10];
    const float* Whh1  = (const float*)d_in[11];
    const float* bih1  = (const float*)d_in[12];
    const float* bhh1  = (const float*)d_in[13];

    float* ws   = (float*)d_ws;
    float* sa   = ws;                         // 1024
    float* sb   = sa   + NN;                  // 1024
    float* hdot = sb   + NN;                  // 1024
    float* hb   = hdot + NN;                  // 1024
    float* sr   = hb   + NN;                  // 1024*1024
    float* ssum = sr   + (size_t)NN * NN;     // 1024*1024

    k_main<<<GRUB + RELB, 512, 0, stream>>>(x, rel, W, fc_w,
                                            Wih0, Whh0, bih0, bhh0,
                                            Wih1, Whh1, bih1, bhh1,
                                            sa, sb, hdot, hb, sr, ssum);
    k2<<<NN, 256, 0, stream>>>(sa, sb, hdot, hb, sr, ssum,
                               b, fc_b, (float*)d_out);
}

// Round 15
// 389.378 us; speedup vs baseline: 1.0230x; 1.0230x over previous
//
#include <hip/hip_runtime.h>
#include <cstddef>

#define NN 1024
#define DD 6
#define TT 60
#define HH 64
#define NEGV  (-10000.0f)
#define SLOPEV (0.01f)
#define GRUB 64           // GRU blocks: 16 samples, 8 waves (512 thr)
#define RELB 448          // 64+448 = 512 blocks = 2/CU, one generation

// LDS float offsets
#define BH0O  0           // h0 f16, 2 parities x [n][36]  (1152 floats)
#define BH1O  1152        // h1 f16, 2 parities x [n][36]
#define XH    2304        // x f16 [(t*16+n)*4 floats]     (3840)
#define HEP   6144        // h1 f32 epilogue staging [j][17] (1088)
#define SMEMF 7232        // 28.9 KB

typedef _Float16 v8h __attribute__((ext_vector_type(8)));
typedef float    v4f __attribute__((ext_vector_type(4)));

#define MF(a, b, c) __builtin_amdgcn_mfma_f32_16x16x32_f16((a), (b), (c), 0, 0, 0)

__device__ __forceinline__ float sig_(float x)  { return 1.0f / (1.0f + __expf(-x)); }
__device__ __forceinline__ float tanh_(float x) { return 1.0f - 2.0f / (__expf(2.0f * x) + 1.0f); }
__device__ __forceinline__ float bcf_(const float a, const float b) {
    return __builtin_bit_cast(float, __builtin_amdgcn_cvt_pkrtz(a, b));
}
__device__ __forceinline__ v8h zero8() {
    v8h r;
    #pragma unroll
    for (int j = 0; j < 8; ++j) r[j] = (_Float16)0.f;
    return r;
}
__device__ __forceinline__ v8h pack8(const float* __restrict__ p) {
    v8h r;
    #pragma unroll
    for (int j = 0; j < 8; ++j) r[j] = (_Float16)p[j];
    return r;
}
__device__ __forceinline__ v8h pack6(const float* __restrict__ p) {
    v8h r = zero8();
    #pragma unroll
    for (int j = 0; j < 6; ++j) r[j] = (_Float16)p[j];
    return r;
}

// ---------------------------------------------------------------------------
// k_main: 512 blocks x 512 threads (2/CU, one generation).
//   blocks [0,64): MFMA GRU, 16 samples, 8 waves, ONE barrier/step.
//     C-fragment insight: for each 16x16 tile, lane (quad,mc) holds rows
//     16wt+quad*4+e, col mc — the SAME (j,n) across the wave's r/z/xn/hn
//     tiles. So the GRU update runs fully in-register (h_prev persists
//     per-lane); the only LDS per step is the packed-f16 h exchange
//     (1 ds_write_b64 + 2-4 ds_read_b128), parity double-buffered.
//     R12-R14's preact round-trip (16 stride-19 ds_writes + 20 ds_reads
//     + 2nd barrier, 2.9M bank conflicts) is deleted.
//   blocks [64,512): rel streaming, no barriers (unchanged, verified).
// ---------------------------------------------------------------------------
__global__ __launch_bounds__(512)
void k_main(const float* __restrict__ x, const float* __restrict__ rel,
            const float* __restrict__ W, const float* __restrict__ fc_w,
            const float* __restrict__ Wih0, const float* __restrict__ Whh0,
            const float* __restrict__ bih0, const float* __restrict__ bhh0,
            const float* __restrict__ Wih1, const float* __restrict__ Whh1,
            const float* __restrict__ bih1, const float* __restrict__ bhh1,
            float* __restrict__ sa, float* __restrict__ sb,
            float* __restrict__ hdot, float* __restrict__ hb,
            float* __restrict__ sr, float* __restrict__ ssum)
{
    __shared__ float smem[SMEMF];
    const int tid = threadIdx.x;

    if (blockIdx.x >= GRUB) {
        // ---------------- relation streaming ----------------
        const float* __restrict__ Wv = W + 2 * HH;     // uniform -> s_loads
        const unsigned base = (unsigned)(blockIdx.x - GRUB) * 512 + tid;
        for (unsigned p = base; p < (unsigned)(NN * NN); p += (unsigned)RELB * 512) {
            const float4* b4 = (const float4*)(rel + (size_t)p * 64);
            float4 v[16];
            #pragma unroll
            for (int q = 0; q < 16; ++q) v[q] = b4[q];
            float d0 = 0.f, d1 = 0.f, s0 = 0.f, s1 = 0.f;
            #pragma unroll
            for (int q = 0; q < 16; ++q) {
                d0 += v[q].x * Wv[4*q]   + v[q].z * Wv[4*q+2];
                d1 += v[q].y * Wv[4*q+1] + v[q].w * Wv[4*q+3];
                s0 += v[q].x + v[q].z;
                s1 += v[q].y + v[q].w;
            }
            sr[p]   = d0 + d1;
            ssum[p] = s0 + s1;
        }
        return;
    }

    // ---------------- GRU ----------------
    const int w    = tid >> 6;          // wave 0..7
    const int lane = tid & 63;
    const int quad = lane >> 4;
    const int mc   = lane & 15;
    const int nb   = blockIdx.x * 16;
    const bool isL0 = (w < 4);
    const int wt   = isL0 ? w : (w - 4);   // row-tile index within layer

    // ---- stage x as f16; zero both parities of BH0/BH1 ----
    for (int idx = tid; idx < TT * 16; idx += 512) {
        const int t = idx >> 4, n = idx & 15;
        const float* xp = x + (size_t)(nb + n) * (DD * TT) + t;
        float4 pk;
        pk.x = bcf_(xp[0],   xp[60]);
        pk.y = bcf_(xp[120], xp[180]);
        pk.z = bcf_(xp[240], xp[300]);
        pk.w = 0.f;
        *(float4*)(smem + XH + idx * 4) = pk;
    }
    for (int idx = tid; idx < 2304; idx += 512) smem[idx] = 0.f;

    // ---- persistent A-fragments ----
    const int r0row = 16 * wt + mc;
    const int zrow  = 64 + 16 * wt + mc;
    const int nrow  = 128 + 16 * wt + mc;
    v8h F0 = zero8(), F1 = zero8(), F2 = zero8(), F3 = zero8();
    v8h F4 = zero8(), F5 = zero8(), F6 = zero8(), F7 = zero8();
    v8h F8 = zero8(), F9 = zero8(), F10 = zero8(), F11 = zero8();
    v8h Xr = zero8(), Xz = zero8(), Xn = zero8();
    if (isL0) {
        F0 = pack8(Whh0 + (size_t)r0row * HH + quad * 8);         // Ar0
        F1 = pack8(Whh0 + (size_t)r0row * HH + 32 + quad * 8);    // Ar1
        F2 = pack8(Whh0 + (size_t)zrow  * HH + quad * 8);         // Az0
        F3 = pack8(Whh0 + (size_t)zrow  * HH + 32 + quad * 8);    // Az1
        F4 = pack8(Whh0 + (size_t)nrow  * HH + quad * 8);         // An0
        F5 = pack8(Whh0 + (size_t)nrow  * HH + 32 + quad * 8);    // An1
        if (quad == 0) {
            Xr = pack6(Wih0 + r0row * DD);
            Xz = pack6(Wih0 + zrow  * DD);
            Xn = pack6(Wih0 + nrow  * DD);
        }
    } else {
        F0 = pack8(Wih1 + (size_t)r0row * HH + quad * 8);         // R0
        F1 = pack8(Wih1 + (size_t)r0row * HH + 32 + quad * 8);    // R1
        F2 = pack8(Whh1 + (size_t)r0row * HH + quad * 8);         // R2
        F3 = pack8(Whh1 + (size_t)r0row * HH + 32 + quad * 8);    // R3
        F4 = pack8(Wih1 + (size_t)zrow * HH + quad * 8);          // Z0
        F5 = pack8(Wih1 + (size_t)zrow * HH + 32 + quad * 8);     // Z1
        F6 = pack8(Whh1 + (size_t)zrow * HH + quad * 8);          // Z2
        F7 = pack8(Whh1 + (size_t)zrow * HH + 32 + quad * 8);     // Z3
        F8 = pack8(Wih1 + (size_t)nrow * HH + quad * 8);          // Nx0
        F9 = pack8(Wih1 + (size_t)nrow * HH + 32 + quad * 8);     // Nx1
        F10 = pack8(Whh1 + (size_t)nrow * HH + quad * 8);         // Nh0
        F11 = pack8(Whh1 + (size_t)nrow * HH + 32 + quad * 8);    // Nh1
    }

    // ---- biases at C rows (lane's 4 rows = 16wt + quad*4 + e) ----
    float bR[4], bZ[4], bXn[4], bHn[4];
    #pragma unroll
    for (int e = 0; e < 4; ++e) {
        const int cr = 16 * wt + quad * 4 + e;
        if (isL0) {
            bR[e]  = bih0[cr] + bhh0[cr];
            bZ[e]  = bih0[64 + cr] + bhh0[64 + cr];
            bXn[e] = bih0[128 + cr];
            bHn[e] = bhh0[128 + cr];
        } else {
            bR[e]  = bih1[cr] + bhh1[cr];
            bZ[e]  = bih1[64 + cr] + bhh1[64 + cr];
            bXn[e] = bih1[128 + cr];
            bHn[e] = bhh1[128 + cr];
        }
    }

    float hp[4] = {0.f, 0.f, 0.f, 0.f};   // persistent h[j=16wt+quad*4+e][n=mc]
    __syncthreads();

    auto ldb = [&](const float* basep, int win) -> v8h {
        return __builtin_bit_cast(v8h,
            *(const float4*)(basep + mc * 36 + win * 16 + quad * 4));
    };
    auto sth = [&](float* basep) {
        float2 pk;
        pk.x = bcf_(hp[0], hp[1]);
        pk.y = bcf_(hp[2], hp[3]);
        *(float2*)(basep + mc * 36 + 8 * wt + 2 * quad) = pk;
    };
    auto gupd = [&](const v4f& cr, const v4f& cz, const v4f& cx, const v4f& ch) {
        #pragma unroll
        for (int e = 0; e < 4; ++e) {
            const float r  = sig_(cr[e]);
            const float z  = sig_(cz[e]);
            const float nv = tanh_(cx[e] + r * ch[e]);
            hp[e] = (1.f - z) * nv + z * hp[e];
        }
    };

    for (int i = 0; i <= TT; ++i) {
        const int rbo = (i & 1) * 576;          // read parity
        const int wbo = 576 - rbo;              // write parity
        if (isL0) {
            if (i < TT) {
                const v8h b0 = ldb(smem + BH0O + rbo, 0);
                const v8h b1 = ldb(smem + BH0O + rbo, 1);
                const float4 xl = *(const float4*)(smem + XH + (i * 16 + mc) * 4);
                v8h bx = zero8();
                if (quad == 0) bx = __builtin_bit_cast(v8h, xl);

                v4f cr = {bR[0], bR[1], bR[2], bR[3]};
                cr = MF(F0, b0, cr); cr = MF(F1, b1, cr); cr = MF(Xr, bx, cr);
                v4f cz = {bZ[0], bZ[1], bZ[2], bZ[3]};
                cz = MF(F2, b0, cz); cz = MF(F3, b1, cz); cz = MF(Xz, bx, cz);
                v4f ch = {bHn[0], bHn[1], bHn[2], bHn[3]};
                ch = MF(F4, b0, ch); ch = MF(F5, b1, ch);
                v4f cx = {bXn[0], bXn[1], bXn[2], bXn[3]};
                cx = MF(Xn, bx, cx);

                gupd(cr, cz, cx, ch);
                sth(smem + BH0O + wbo);
            }
        } else {
            if (i >= 1) {
                const v8h g0 = ldb(smem + BH0O + rbo, 0);   // h0 after t=i-1
                const v8h g1 = ldb(smem + BH0O + rbo, 1);
                const v8h g2 = ldb(smem + BH1O + rbo, 0);   // h1 after t=i-2
                const v8h g3 = ldb(smem + BH1O + rbo, 1);

                v4f cr = {bR[0], bR[1], bR[2], bR[3]};
                cr = MF(F0, g0, cr); cr = MF(F1, g1, cr);
                cr = MF(F2, g2, cr); cr = MF(F3, g3, cr);
                v4f cz = {bZ[0], bZ[1], bZ[2], bZ[3]};
                cz = MF(F4, g0, cz); cz = MF(F5, g1, cz);
                cz = MF(F6, g2, cz); cz = MF(F7, g3, cz);
                v4f cx = {bXn[0], bXn[1], bXn[2], bXn[3]};
                cx = MF(F8, g0, cx); cx = MF(F9, g1, cx);
                v4f ch = {bHn[0], bHn[1], bHn[2], bHn[3]};
                ch = MF(F10, g2, ch); ch = MF(F11, g3, ch);

                gupd(cr, cz, cx, ch);
                sth(smem + BH1O + wbo);
            }
        }
        __syncthreads();
    }

    // ---------------- epilogue ----------------
    if (!isL0) {
        #pragma unroll
        for (int e = 0; e < 4; ++e)
            smem[HEP + (16 * wt + quad * 4 + e) * 17 + mc] = hp[e];
    }
    __syncthreads();
    if (isL0) {
        const int n = lane >> 2, p = lane & 3;
        const float* __restrict__ wp = (w == 0) ? W : (w == 1) ? (W + HH)
                                     : (w == 2) ? fc_w : (fc_w + HH);
        float v = 0.f;
        #pragma unroll
        for (int q = 0; q < 16; ++q) {
            const int j = p * 16 + q;
            v += smem[HEP + j * 17 + n] * wp[j];
        }
        v += __shfl_down(v, 2);
        v += __shfl_down(v, 1);
        if (p == 0) {
            float* dst = (w == 0) ? sa : (w == 1) ? sb : (w == 2) ? hdot : hb;
            dst[nb + n] = v;
        }
    }
}

// ---------------------------------------------------------------------------
// k2: per row i — masked leaky scores, exact masked-softmax semantics,
// out_i = hdot_i + (sum_j e_j*m_j*hb_j)/denom + fc_b.   (verified R2-R14)
// ---------------------------------------------------------------------------
__global__ __launch_bounds__(256)
void k2(const float* __restrict__ sa, const float* __restrict__ sb,
        const float* __restrict__ hdot, const float* __restrict__ hb,
        const float* __restrict__ sr, const float* __restrict__ ssum,
        const float* __restrict__ bscal, const float* __restrict__ fc_b,
        float* __restrict__ out)
{
    __shared__ float red[12];
    const int i   = blockIdx.x;
    const int tid = threadIdx.x;
    const int j4  = tid * 4;
    const float sai = sa[i] + bscal[0];

    const float4 srv = *(const float4*)(sr   + (size_t)i * NN + j4);
    const float4 ssv = *(const float4*)(ssum + (size_t)i * NN + j4);
    const float4 sbv = *(const float4*)(sb + j4);

    float tv[4], mk[4];
    float mloc = -3.4e38f;
    {
        const float srq[4] = {srv.x, srv.y, srv.z, srv.w};
        const float ssq[4] = {ssv.x, ssv.y, ssv.z, ssv.w};
        const float sbq[4] = {sbv.x, sbv.y, sbv.z, sbv.w};
        #pragma unroll
        for (int q = 0; q < 4; ++q) {
            float wv = sai + sbq[q] + srq[q];
            wv = (wv >= 0.0f) ? wv : SLOPEV * wv;
            const float m = (ssq[q] != 0.0f) ? 1.0f : 0.0f;
            float tt = m * wv;
            tt = (tt == 0.0f) ? NEGV : tt;
            tv[q] = tt; mk[q] = m;
            mloc = fmaxf(mloc, tt);
        }
    }
    #pragma unroll
    for (int off = 32; off >= 1; off >>= 1) mloc = fmaxf(mloc, __shfl_xor(mloc, off));
    if ((tid & 63) == 0) red[tid >> 6] = mloc;
    __syncthreads();
    const float mx = fmaxf(fmaxf(red[0], red[1]), fmaxf(red[2], red[3]));

    const float4 hbv = *(const float4*)(hb + j4);
    const float hbq[4] = {hbv.x, hbv.y, hbv.z, hbv.w};
    float sloc = 0.0f, vloc = 0.0f;
    #pragma unroll
    for (int q = 0; q < 4; ++q) {
        const float e = __expf(tv[q] - mx);   // masked -> exp(-1e4 - mx) == 0
        sloc += e;
        vloc += e * mk[q] * hbq[q];
    }
    #pragma unroll
    for (int off = 32; off >= 1; off >>= 1) {
        sloc += __shfl_xor(sloc, off);
        vloc += __shfl_xor(vloc, off);
    }
    if ((tid & 63) == 0) { red[4 + (tid >> 6)] = sloc; red[8 + (tid >> 6)] = vloc; }
    __syncthreads();
    if (tid == 0) {
        const float denom = red[4] + red[5] + red[6] + red[7];
        const float vsum  = red[8] + red[9] + red[10] + red[11];
        out[i] = hdot[i] + vsum / denom + fc_b[0];
    }
}

// ---------------------------------------------------------------------------
extern "C" void kernel_launch(void* const* d_in, const int* in_sizes, int n_in,
                              void* d_out, int out_size, void* d_ws, size_t ws_size,
                              hipStream_t stream)
{
    const float* x     = (const float*)d_in[0];
    const float* rel   = (const float*)d_in[1];
    const float* W     = (const float*)d_in[2];
    const float* b     = (const float*)d_in[3];
    const float* fc_w  = (const float*)d_in[4];
    const float* fc_b  = (const float*)d_in[5];
    const float* Wih0  = (const float*)d_in[6];
    const float* Whh0  = (const float*)d_in[7];
    const float* bih0  = (const float*)d_in[8];
    const float* bhh0  = (const float*)d_in[9];
    const float* Wih1  = (const float*)d_in[10];
    const float* Whh1  = (const float*)d_in[11];
    const float* bih1  = (const float*)d_in[12];
    const float* bhh1  = (const float*)d_in[13];

    float* ws   = (float*)d_ws;
    float* sa   = ws;                         // 1024
    float* sb   = sa   + NN;                  // 1024
    float* hdot = sb   + NN;                  // 1024
    float* hb   = hdot + NN;                  // 1024
    float* sr   = hb   + NN;                  // 1024*1024
    float* ssum = sr   + (size_t)NN * NN;     // 1024*1024

    k_main<<<GRUB + RELB, 512, 0, stream>>>(x, rel, W, fc_w,
                                            Wih0, Whh0, bih0, bhh0,
                                            Wih1, Whh1, bih1, bhh1,
                                            sa, sb, hdot, hb, sr, ssum);
    k2<<<NN, 256, 0, stream>>>(sa, sb, hdot, hb, sr, ssum,
                               b, fc_b, (float*)d_out);
}

// Round 16
// 384.668 us; speedup vs baseline: 1.0356x; 1.0122x over previous
//
#include <hip/hip_runtime.h>
#include <cstddef>

#define NN 1024
#define DD 6
#define TT 60
#define HH 64
#define NEGV  (-10000.0f)
#define SLOPEV (0.01f)
#define GRUB 64           // GRU blocks: 16 samples, 8 waves (512 thr)
#define RELB 448          // 64+448 = 512 blocks = 2/CU, one generation
#define RELW (RELB * 8)   // rel waves total
#define NGRP (NN * NN / 64)

// LDS float offsets
#define BH0O  0           // h0 f16, 2 parities x [n][36]  (1152 floats)
#define BH1O  1152        // h1 f16, 2 parities x [n][36]
#define XH    2304        // x f16 [(t*16+n)*4 floats]     (3840)
#define HEP   6144        // h1 f32 epilogue staging [j][17] (1088)
#define SMEMF 7232        // 28.9 KB

typedef _Float16 v8h __attribute__((ext_vector_type(8)));
typedef float    v4f __attribute__((ext_vector_type(4)));

#define MF(a, b, c) __builtin_amdgcn_mfma_f32_16x16x32_f16((a), (b), (c), 0, 0, 0)

__device__ __forceinline__ float sig_(float x)  { return 1.0f / (1.0f + __expf(-x)); }
__device__ __forceinline__ float tanh_(float x) { return 1.0f - 2.0f / (__expf(2.0f * x) + 1.0f); }
__device__ __forceinline__ float bcf_(const float a, const float b) {
    return __builtin_bit_cast(float, __builtin_amdgcn_cvt_pkrtz(a, b));
}
__device__ __forceinline__ v8h zero8() {
    v8h r;
    #pragma unroll
    for (int j = 0; j < 8; ++j) r[j] = (_Float16)0.f;
    return r;
}
__device__ __forceinline__ v8h pack8(const float* __restrict__ p) {
    v8h r;
    #pragma unroll
    for (int j = 0; j < 8; ++j) r[j] = (_Float16)p[j];
    return r;
}
__device__ __forceinline__ v8h pack6(const float* __restrict__ p) {
    v8h r = zero8();
    #pragma unroll
    for (int j = 0; j < 6; ++j) r[j] = (_Float16)p[j];
    return r;
}

// ---------------------------------------------------------------------------
// k_main: 512 blocks x 512 threads (2/CU, one generation).
//   blocks [0,64): MFMA GRU — unchanged from R15 (in-register gate update,
//     one barrier/step, parity-dbuf f16 h exchange; absmax 0.0039 verified).
//   blocks [64,512): rel streaming, NEW per-instruction-coalesced pattern:
//     each wave owns a 64-pair group (16 KB) and reads it as 16 contiguous
//     1 KB wave loads (lane l, load q -> float4 at g*4096+q*256+l*4).
//     Lane's chunk index within a pair is CONSTANT (l&15) -> fixed Wv
//     float4; partials reduced across the 16-lane group via 4 shfl_xor.
//     R15's 1-thread/pair layout thrashed L1 (256B-stride gathers, 256KB
//     demand vs 32KB L1): rel ran at ~2.1 TB/s. Every byte now read once.
// ---------------------------------------------------------------------------
__global__ __launch_bounds__(512)
void k_main(const float* __restrict__ x, const float* __restrict__ rel,
            const float* __restrict__ W, const float* __restrict__ fc_w,
            const float* __restrict__ Wih0, const float* __restrict__ Whh0,
            const float* __restrict__ bih0, const float* __restrict__ bhh0,
            const float* __restrict__ Wih1, const float* __restrict__ Whh1,
            const float* __restrict__ bih1, const float* __restrict__ bhh1,
            float* __restrict__ sa, float* __restrict__ sb,
            float* __restrict__ hdot, float* __restrict__ hb,
            float* __restrict__ sr, float* __restrict__ ssum)
{
    __shared__ float smem[SMEMF];
    const int tid = threadIdx.x;

    if (blockIdx.x >= GRUB) {
        // ---------------- relation streaming (coalesced groups) -------------
        const int lane = tid & 63;
        const int l16  = lane & 15;
        const int sub  = lane >> 4;
        const float4 wv4 = *(const float4*)(W + 2 * HH + l16 * 4);
        const unsigned wid = (unsigned)(blockIdx.x - GRUB) * 8 + (tid >> 6);
        for (unsigned g = wid; g < (unsigned)NGRP; g += RELW) {
            const float4* bp = (const float4*)(rel + (size_t)g * 4096) + lane;
            float4 v[16];
            #pragma unroll
            for (int q = 0; q < 16; ++q) v[q] = bp[q * 64];   // 1 KB contiguous / load
            float dt[16], sm[16];
            #pragma unroll
            for (int q = 0; q < 16; ++q) {
                dt[q] = v[q].x * wv4.x + v[q].y * wv4.y + v[q].z * wv4.z + v[q].w * wv4.w;
                sm[q] = (v[q].x + v[q].y) + (v[q].z + v[q].w);
            }
            #pragma unroll
            for (int m = 1; m <= 8; m <<= 1) {
                #pragma unroll
                for (int q = 0; q < 16; ++q) {
                    dt[q] += __shfl_xor(dt[q], m);
                    sm[q] += __shfl_xor(sm[q], m);
                }
            }
            if (l16 == 0) {
                #pragma unroll
                for (int q = 0; q < 16; ++q) {
                    const unsigned p = g * 64 + q * 4 + sub;
                    sr[p]   = dt[q];
                    ssum[p] = sm[q];
                }
            }
        }
        return;
    }

    // ---------------- GRU (unchanged, R15-verified) ----------------
    const int w    = tid >> 6;          // wave 0..7
    const int lane = tid & 63;
    const int quad = lane >> 4;
    const int mc   = lane & 15;
    const int nb   = blockIdx.x * 16;
    const bool isL0 = (w < 4);
    const int wt   = isL0 ? w : (w - 4);   // row-tile index within layer

    // ---- stage x as f16; zero both parities of BH0/BH1 ----
    for (int idx = tid; idx < TT * 16; idx += 512) {
        const int t = idx >> 4, n = idx & 15;
        const float* xp = x + (size_t)(nb + n) * (DD * TT) + t;
        float4 pk;
        pk.x = bcf_(xp[0],   xp[60]);
        pk.y = bcf_(xp[120], xp[180]);
        pk.z = bcf_(xp[240], xp[300]);
        pk.w = 0.f;
        *(float4*)(smem + XH + idx * 4) = pk;
    }
    for (int idx = tid; idx < 2304; idx += 512) smem[idx] = 0.f;

    // ---- persistent A-fragments ----
    const int r0row = 16 * wt + mc;
    const int zrow  = 64 + 16 * wt + mc;
    const int nrow  = 128 + 16 * wt + mc;
    v8h F0 = zero8(), F1 = zero8(), F2 = zero8(), F3 = zero8();
    v8h F4 = zero8(), F5 = zero8(), F6 = zero8(), F7 = zero8();
    v8h F8 = zero8(), F9 = zero8(), F10 = zero8(), F11 = zero8();
    v8h Xr = zero8(), Xz = zero8(), Xn = zero8();
    if (isL0) {
        F0 = pack8(Whh0 + (size_t)r0row * HH + quad * 8);         // Ar0
        F1 = pack8(Whh0 + (size_t)r0row * HH + 32 + quad * 8);    // Ar1
        F2 = pack8(Whh0 + (size_t)zrow  * HH + quad * 8);         // Az0
        F3 = pack8(Whh0 + (size_t)zrow  * HH + 32 + quad * 8);    // Az1
        F4 = pack8(Whh0 + (size_t)nrow  * HH + quad * 8);         // An0
        F5 = pack8(Whh0 + (size_t)nrow  * HH + 32 + quad * 8);    // An1
        if (quad == 0) {
            Xr = pack6(Wih0 + r0row * DD);
            Xz = pack6(Wih0 + zrow  * DD);
            Xn = pack6(Wih0 + nrow  * DD);
        }
    } else {
        F0 = pack8(Wih1 + (size_t)r0row * HH + quad * 8);         // R0
        F1 = pack8(Wih1 + (size_t)r0row * HH + 32 + quad * 8);    // R1
        F2 = pack8(Whh1 + (size_t)r0row * HH + quad * 8);         // R2
        F3 = pack8(Whh1 + (size_t)r0row * HH + 32 + quad * 8);    // R3
        F4 = pack8(Wih1 + (size_t)zrow * HH + quad * 8);          // Z0
        F5 = pack8(Wih1 + (size_t)zrow * HH + 32 + quad * 8);     // Z1
        F6 = pack8(Whh1 + (size_t)zrow * HH + quad * 8);          // Z2
        F7 = pack8(Whh1 + (size_t)zrow * HH + 32 + quad * 8);     // Z3
        F8 = pack8(Wih1 + (size_t)nrow * HH + quad * 8);          // Nx0
        F9 = pack8(Wih1 + (size_t)nrow * HH + 32 + quad * 8);     // Nx1
        F10 = pack8(Whh1 + (size_t)nrow * HH + quad * 8);         // Nh0
        F11 = pack8(Whh1 + (size_t)nrow * HH + 32 + quad * 8);    // Nh1
    }

    // ---- biases at C rows (lane's 4 rows = 16wt + quad*4 + e) ----
    float bR[4], bZ[4], bXn[4], bHn[4];
    #pragma unroll
    for (int e = 0; e < 4; ++e) {
        const int cr = 16 * wt + quad * 4 + e;
        if (isL0) {
            bR[e]  = bih0[cr] + bhh0[cr];
            bZ[e]  = bih0[64 + cr] + bhh0[64 + cr];
            bXn[e] = bih0[128 + cr];
            bHn[e] = bhh0[128 + cr];
        } else {
            bR[e]  = bih1[cr] + bhh1[cr];
            bZ[e]  = bih1[64 + cr] + bhh1[64 + cr];
            bXn[e] = bih1[128 + cr];
            bHn[e] = bhh1[128 + cr];
        }
    }

    float hp[4] = {0.f, 0.f, 0.f, 0.f};   // persistent h[j=16wt+quad*4+e][n=mc]
    __syncthreads();

    auto ldb = [&](const float* basep, int win) -> v8h {
        return __builtin_bit_cast(v8h,
            *(const float4*)(basep + mc * 36 + win * 16 + quad * 4));
    };
    auto sth = [&](float* basep) {
        float2 pk;
        pk.x = bcf_(hp[0], hp[1]);
        pk.y = bcf_(hp[2], hp[3]);
        *(float2*)(basep + mc * 36 + 8 * wt + 2 * quad) = pk;
    };
    auto gupd = [&](const v4f& cr, const v4f& cz, const v4f& cx, const v4f& ch) {
        #pragma unroll
        for (int e = 0; e < 4; ++e) {
            const float r  = sig_(cr[e]);
            const float z  = sig_(cz[e]);
            const float nv = tanh_(cx[e] + r * ch[e]);
            hp[e] = (1.f - z) * nv + z * hp[e];
        }
    };

    for (int i = 0; i <= TT; ++i) {
        const int rbo = (i & 1) * 576;          // read parity
        const int wbo = 576 - rbo;              // write parity
        if (isL0) {
            if (i < TT) {
                const v8h b0 = ldb(smem + BH0O + rbo, 0);
                const v8h b1 = ldb(smem + BH0O + rbo, 1);
                const float4 xl = *(const float4*)(smem + XH + (i * 16 + mc) * 4);
                v8h bx = zero8();
                if (quad == 0) bx = __builtin_bit_cast(v8h, xl);

                v4f cr = {bR[0], bR[1], bR[2], bR[3]};
                cr = MF(F0, b0, cr); cr = MF(F1, b1, cr); cr = MF(Xr, bx, cr);
                v4f cz = {bZ[0], bZ[1], bZ[2], bZ[3]};
                cz = MF(F2, b0, cz); cz = MF(F3, b1, cz); cz = MF(Xz, bx, cz);
                v4f ch = {bHn[0], bHn[1], bHn[2], bHn[3]};
                ch = MF(F4, b0, ch); ch = MF(F5, b1, ch);
                v4f cx = {bXn[0], bXn[1], bXn[2], bXn[3]};
                cx = MF(Xn, bx, cx);

                gupd(cr, cz, cx, ch);
                sth(smem + BH0O + wbo);
            }
        } else {
            if (i >= 1) {
                const v8h g0 = ldb(smem + BH0O + rbo, 0);   // h0 after t=i-1
                const v8h g1 = ldb(smem + BH0O + rbo, 1);
                const v8h g2 = ldb(smem + BH1O + rbo, 0);   // h1 after t=i-2
                const v8h g3 = ldb(smem + BH1O + rbo, 1);

                v4f cr = {bR[0], bR[1], bR[2], bR[3]};
                cr = MF(F0, g0, cr); cr = MF(F1, g1, cr);
                cr = MF(F2, g2, cr); cr = MF(F3, g3, cr);
                v4f cz = {bZ[0], bZ[1], bZ[2], bZ[3]};
                cz = MF(F4, g0, cz); cz = MF(F5, g1, cz);
                cz = MF(F6, g2, cz); cz = MF(F7, g3, cz);
                v4f cx = {bXn[0], bXn[1], bXn[2], bXn[3]};
                cx = MF(F8, g0, cx); cx = MF(F9, g1, cx);
                v4f ch = {bHn[0], bHn[1], bHn[2], bHn[3]};
                ch = MF(F10, g2, ch); ch = MF(F11, g3, ch);

                gupd(cr, cz, cx, ch);
                sth(smem + BH1O + wbo);
            }
        }
        __syncthreads();
    }

    // ---------------- epilogue ----------------
    if (!isL0) {
        #pragma unroll
        for (int e = 0; e < 4; ++e)
            smem[HEP + (16 * wt + quad * 4 + e) * 17 + mc] = hp[e];
    }
    __syncthreads();
    if (isL0) {
        const int n = lane >> 2, p = lane & 3;
        const float* __restrict__ wp = (w == 0) ? W : (w == 1) ? (W + HH)
                                     : (w == 2) ? fc_w : (fc_w + HH);
        float v = 0.f;
        #pragma unroll
        for (int q = 0; q < 16; ++q) {
            const int j = p * 16 + q;
            v += smem[HEP + j * 17 + n] * wp[j];
        }
        v += __shfl_down(v, 2);
        v += __shfl_down(v, 1);
        if (p == 0) {
            float* dst = (w == 0) ? sa : (w == 1) ? sb : (w == 2) ? hdot : hb;
            dst[nb + n] = v;
        }
    }
}

// ---------------------------------------------------------------------------
// k2: per row i — masked leaky scores, exact masked-softmax semantics,
// out_i = hdot_i + (sum_j e_j*m_j*hb_j)/denom + fc_b.   (verified R2-R15)
// ---------------------------------------------------------------------------
__global__ __launch_bounds__(256)
void k2(const float* __restrict__ sa, const float* __restrict__ sb,
        const float* __restrict__ hdot, const float* __restrict__ hb,
        const float* __restrict__ sr, const float* __restrict__ ssum,
        const float* __restrict__ bscal, const float* __restrict__ fc_b,
        float* __restrict__ out)
{
    __shared__ float red[12];
    const int i   = blockIdx.x;
    const int tid = threadIdx.x;
    const int j4  = tid * 4;
    const float sai = sa[i] + bscal[0];

    const float4 srv = *(const float4*)(sr   + (size_t)i * NN + j4);
    const float4 ssv = *(const float4*)(ssum + (size_t)i * NN + j4);
    const float4 sbv = *(const float4*)(sb + j4);

    float tv[4], mk[4];
    float mloc = -3.4e38f;
    {
        const float srq[4] = {srv.x, srv.y, srv.z, srv.w};
        const float ssq[4] = {ssv.x, ssv.y, ssv.z, ssv.w};
        const float sbq[4] = {sbv.x, sbv.y, sbv.z, sbv.w};
        #pragma unroll
        for (int q = 0; q < 4; ++q) {
            float wv = sai + sbq[q] + srq[q];
            wv = (wv >= 0.0f) ? wv : SLOPEV * wv;
            const float m = (ssq[q] != 0.0f) ? 1.0f : 0.0f;
            float tt = m * wv;
            tt = (tt == 0.0f) ? NEGV : tt;
            tv[q] = tt; mk[q] = m;
            mloc = fmaxf(mloc, tt);
        }
    }
    #pragma unroll
    for (int off = 32; off >= 1; off >>= 1) mloc = fmaxf(mloc, __shfl_xor(mloc, off));
    if ((tid & 63) == 0) red[tid >> 6] = mloc;
    __syncthreads();
    const float mx = fmaxf(fmaxf(red[0], red[1]), fmaxf(red[2], red[3]));

    const float4 hbv = *(const float4*)(hb + j4);
    const float hbq[4] = {hbv.x, hbv.y, hbv.z, hbv.w};
    float sloc = 0.0f, vloc = 0.0f;
    #pragma unroll
    for (int q = 0; q < 4; ++q) {
        const float e = __expf(tv[q] - mx);   // masked -> exp(-1e4 - mx) == 0
        sloc += e;
        vloc += e * mk[q] * hbq[q];
    }
    #pragma unroll
    for (int off = 32; off >= 1; off >>= 1) {
        sloc += __shfl_xor(sloc, off);
        vloc += __shfl_xor(vloc, off);
    }
    if ((tid & 63) == 0) { red[4 + (tid >> 6)] = sloc; red[8 + (tid >> 6)] = vloc; }
    __syncthreads();
    if (tid == 0) {
        const float denom = red[4] + red[5] + red[6] + red[7];
        const float vsum  = red[8] + red[9] + red[10] + red[11];
        out[i] = hdot[i] + vsum / denom + fc_b[0];
    }
}

// ---------------------------------------------------------------------------
extern "C" void kernel_launch(void* const* d_in, const int* in_sizes, int n_in,
                              void* d_out, int out_size, void* d_ws, size_t ws_size,
                              hipStream_t stream)
{
    const float* x     = (const float*)d_in[0];
    const float* rel   = (const float*)d_in[1];
    const float* W     = (const float*)d_in[2];
    const float* b     = (const float*)d_in[3];
    const float* fc_w  = (const float*)d_in[4];
    const float* fc_b  = (const float*)d_in[5];
    const float* Wih0  = (const float*)d_in[6];
    const float* Whh0  = (const float*)d_in[7];
    const float* bih0  = (const float*)d_in[8];
    const float* bhh0  = (const float*)d_in[9];
    const float* Wih1  = (const float*)d_in[10];
    const float* Whh1  = (const float*)d_in[11];
    const float* bih1  = (const float*)d_in[12];
    const float* bhh1  = (const float*)d_in[13];

    float* ws   = (float*)d_ws;
    float* sa   = ws;                         // 1024
    float* sb   = sa   + NN;                  // 1024
    float* hdot = sb   + NN;                  // 1024
    float* hb   = hdot + NN;                  // 1024
    float* sr   = hb   + NN;                  // 1024*1024
    float* ssum = sr   + (size_t)NN * NN;     // 1024*1024

    k_main<<<GRUB + RELB, 512, 0, stream>>>(x, rel, W, fc_w,
                                            Wih0, Whh0, bih0, bhh0,
                                            Wih1, Whh1, bih1, bhh1,
                                            sa, sb, hdot, hb, sr, ssum);
    k2<<<NN, 256, 0, stream>>>(sa, sb, hdot, hb, sr, ssum,
                               b, fc_b, (float*)d_out);
}